// Round 8
// baseline (161.789 us; speedup 1.0000x reference)
//
#include <hip/hip_runtime.h>
#include <math.h>

#define Bsz 4096
#define Ssz 200
#define Dsz 64
#define NK  5
#define NT  512
#define ROWH 80    // halves per emb row (160 B); columns XOR-swizzled by (s>>3)&7
#define ATS 208    // att_h row stride (halves)

typedef _Float16 half_t;
typedef _Float16 h2 __attribute__((ext_vector_type(2)));
typedef _Float16 h8 __attribute__((ext_vector_type(8)));
typedef float    f4v __attribute__((ext_vector_type(4)));

__device__ inline h2 shfl_xor_h2(h2 v, int m) {
    int iv = __builtin_bit_cast(int, v);
    iv = __shfl_xor(iv, m);
    return __builtin_bit_cast(h2, iv);
}

__device__ inline h2 pk(float a, float b) {
    return __builtin_bit_cast(h2, __builtin_amdgcn_cvt_pkrtz(a, b));
}

__device__ inline float fast_tanh(float x) {
    float e = __expf(-2.0f * fabsf(x));
    float r = (1.0f - e) / (1.0f + e);
    return copysignf(r, x);
}

__global__ void zero_loss_kernel(float* loss) {
    if (threadIdx.x == 0) *loss = 0.0f;
}

__global__ __launch_bounds__(NT, 8) void tan_kernel(
    const int* __restrict__ x, const float* __restrict__ y,
    const float* __restrict__ emb_table,
    const float* __restrict__ att_w, const float* __restrict__ att_b,
    const float* __restrict__ W0, const float* __restrict__ W1,
    const float* __restrict__ W2, const float* __restrict__ W3,
    const float* __restrict__ W4,
    float* __restrict__ out_logit, float* __restrict__ loss_out)
{
    __shared__ alignas(16) half_t embh[208 * ROWH];   // 33280 B (fp16, swizzled cols)
    __shared__ alignas(16) half_t att_h[NK * ATS];    //  2080 B (logits, then scores)
    __shared__ alignas(16) half_t urph[8][NK][Dsz];   //  5120 B
    __shared__ float wu[18];                          //    72 B
    // total 40552 B -> 4 blocks/CU -> 32 waves/CU

    const int b   = blockIdx.x;
    const int tid = threadIdx.x;
    const int w   = tid >> 6;
    const int l   = tid & 63;
    const int lm  = l & 15;
    const int lq  = l >> 4;

    // ---- Phase A: gather + attention logits via MFMA (B-frags from global) ----
    // C[k][s] = aw(16x64,pad) x emb^T ; per tile: 2 K-steps of 32.
    {
        // A-fragments: aw row lm (zero for lm>=5), d-chunk = 32*st + 8*lq + j
        h8 afrag[2];
#pragma unroll
        for (int st = 0; st < 2; ++st) {
            if (lm < NK) {
                const float4* ap = (const float4*)(att_w + lm * Dsz + 32 * st + 8 * lq);
                float4 a0 = ap[0], a1 = ap[1];
                union { h2 hh[4]; h8 v; } ua;
                ua.hh[0] = pk(a0.x, a0.y); ua.hh[1] = pk(a0.z, a0.w);
                ua.hh[2] = pk(a1.x, a1.y); ua.hh[3] = pk(a1.z, a1.w);
                afrag[st] = ua.v;
            } else {
                afrag[st] = (h8)(half_t)0;
            }
        }
        for (int t = w; t < 13; t += 8) {
            const int s  = 16 * t + lm;                 // up to 207
            const int sc = (s < Ssz) ? s : (Ssz - 1);   // clamp for addressing
            const int xi = x[b * Ssz + sc];
            const float* rowp = emb_table + (size_t)xi * Dsz;
            h8 bfr[2];
#pragma unroll
            for (int st = 0; st < 2; ++st) {
                const float4* bp = (const float4*)(rowp + 32 * st + 8 * lq);
                float4 b0 = bp[0], b1 = bp[1];
                union { h2 hh[4]; h8 v; } ub;
                ub.hh[0] = pk(b0.x, b0.y); ub.hh[1] = pk(b0.z, b0.w);
                ub.hh[2] = pk(b1.x, b1.y); ub.hh[3] = pk(b1.z, b1.w);
                bfr[st] = ub.v;
            }
            f4v acc = {0.f, 0.f, 0.f, 0.f};
            acc = __builtin_amdgcn_mfma_f32_16x16x32_f16(afrag[0], bfr[0], acc, 0, 0, 0);
            acc = __builtin_amdgcn_mfma_f32_16x16x32_f16(afrag[1], bfr[1], acc, 0, 0, 0);
            // store emb row fragment to LDS (swizzled column groups, b128)
            const int js = (s >> 3) & 7;
#pragma unroll
            for (int st = 0; st < 2; ++st) {
                const int gp = (4 * st + lq) ^ js;
                *(h8*)(embh + s * ROWH + gp * 8) = bfr[st];
            }
            // epilogue: C row = k (attr) = lq*4+r, col = s-in-tile = lm
#pragma unroll
            for (int r = 0; r < 4; ++r) {
                const int k = lq * 4 + r;
                if (k < NK)
                    att_h[k * ATS + 16 * t + lm] =
                        (half_t)fast_tanh(acc[r] + att_b[k]);
            }
        }
    }
    __syncthreads();

    // ---- Phase B: softmax over s per k (waves 0..4), fp16 in/out ----
    if (w < NK) {
        const int k = w;
        float vals[4];
        float mx = -1e30f;
#pragma unroll
        for (int j = 0; j < 4; ++j) {
            int s = l + 64 * j;
            vals[j] = (s < Ssz) ? (float)att_h[k * ATS + s] : -1e30f;
            mx = fmaxf(mx, vals[j]);
        }
#pragma unroll
        for (int m = 32; m >= 1; m >>= 1) mx = fmaxf(mx, __shfl_xor(mx, m));
        float sum = 0.f;
#pragma unroll
        for (int j = 0; j < 4; ++j) {
            vals[j] = __expf(vals[j] - mx);
            sum += vals[j];
        }
#pragma unroll
        for (int m = 32; m >= 1; m >>= 1) sum += __shfl_xor(sum, m);
        float inv = 1.0f / sum;
#pragma unroll
        for (int j = 0; j < 4; ++j) {
            int s = l + 64 * j;
            if (s < Ssz) att_h[k * ATS + s] = (half_t)(vals[j] * inv);
        }
    }
    __syncthreads();

    // ---- Phase C: user_rep; thread (c=tid&15 -> d-quad, j=tid>>4 -> s-octet) ----
    {
        const int c = tid & 15;
        const int j = tid >> 4;          // 0..31; octets 0..24 valid
        h2 acc0[NK], acc1[NK];
#pragma unroll
        for (int k = 0; k < NK; ++k) {
            acc0[k] = (h2){(half_t)0, (half_t)0};
            acc1[k] = (h2){(half_t)0, (half_t)0};
        }
        if (j < 25) {
            union { h8 v; h2 hh[4]; } sc[NK];
#pragma unroll
            for (int k = 0; k < NK; ++k)
                sc[k].v = *(const h8*)(att_h + k * ATS + 8 * j);
            const int gp = (c >> 1) ^ (j & 7);   // s>>3 == j within this octet
            const int sub = (c & 1) * 4;
#pragma unroll
            for (int i = 0; i < 8; ++i) {
                const int s = 8 * j + i;
                union { uint2 q; h2 hh[2]; } ue;
                ue.q = *(const uint2*)(embh + s * ROWH + gp * 8 + sub);
#pragma unroll
                for (int k = 0; k < NK; ++k) {
                    half_t f = sc[k].hh[i >> 1][i & 1];
                    h2 s2 = (h2){f, f};
                    acc0[k] += ue.hh[0] * s2;
                    acc1[k] += ue.hh[1] * s2;
                }
            }
        }
        // reduce the wave's 4 j-groups (lane bits 4,5)
#pragma unroll
        for (int k = 0; k < NK; ++k) {
            acc0[k] += shfl_xor_h2(acc0[k], 16);
            acc0[k] += shfl_xor_h2(acc0[k], 32);
            acc1[k] += shfl_xor_h2(acc1[k], 16);
            acc1[k] += shfl_xor_h2(acc1[k], 32);
        }
        if (l < 16) {
#pragma unroll
            for (int k = 0; k < NK; ++k) {
                union { h2 a[2]; uint2 q; } uu;
                uu.a[0] = acc0[k]; uu.a[1] = acc1[k];
                *(uint2*)(&urph[w][k][l * 4]) = uu.q;
            }
        }
    }
    __syncthreads();

    // ---- Phase D: W_user[j] = ur[g(j)] . W_g[r(j)] (8-partial sum folded in) ----
    for (int j = w; j < 18; j += 8) {
        const float* Wp; int g, c0;
        if      (j < 2)  { g = 0; c0 = 0;  Wp = W0; }
        else if (j < 6)  { g = 1; c0 = 2;  Wp = W1; }
        else if (j < 10) { g = 2; c0 = 6;  Wp = W2; }
        else if (j < 12) { g = 3; c0 = 10; Wp = W3; }
        else             { g = 4; c0 = 12; Wp = W4; }
        float urv = 0.f;
#pragma unroll
        for (int jj = 0; jj < 8; ++jj) urv += (float)urph[jj][g][l];
        float p = urv * Wp[(j - c0) * Dsz + l];
#pragma unroll
        for (int m = 32; m >= 1; m >>= 1) p += __shfl_xor(p, m);
        if (l == 0) wu[j] = p;
    }
    __syncthreads();

    // ---- Phase E: per-group softmax -> logits; CE -> atomic loss ----
    if (w == 0) {
        float lossb = 0.f;
        if (l < NK) {
            const int LEN[5] = {2, 4, 4, 2, 6};
            const int C0[5]  = {0, 2, 6, 10, 12};
            const int g = l, c0 = C0[g], len = LEN[g];
            float* op = out_logit + (size_t)b * 18;
            const float* yp = y + (size_t)b * 18;
            float mx = -1e30f;
            for (int j = 0; j < len; ++j) mx = fmaxf(mx, wu[c0 + j]);
            float sum = 0.f;
            for (int j = 0; j < len; ++j) sum += __expf(wu[c0 + j] - mx);
            float inv = 1.0f / sum;
            float lse = mx + __logf(sum);
            for (int j = 0; j < len; ++j) {
                op[c0 + j] = __expf(wu[c0 + j] - mx) * inv;
                lossb += (lse - wu[c0 + j]) * yp[c0 + j];
            }
        }
#pragma unroll
        for (int m = 1; m <= 4; m <<= 1) lossb += __shfl_xor(lossb, m);
        if (l == 0) atomicAdd(loss_out, lossb * (1.0f / Bsz));
    }
}

extern "C" void kernel_launch(void* const* d_in, const int* in_sizes, int n_in,
                              void* d_out, int out_size, void* d_ws, size_t ws_size,
                              hipStream_t stream) {
    const int*   x   = (const int*)d_in[0];
    const float* y   = (const float*)d_in[1];
    const float* emb = (const float*)d_in[2];
    const float* aw  = (const float*)d_in[3];
    const float* ab  = (const float*)d_in[4];
    const float* W0  = (const float*)d_in[5];
    const float* W1  = (const float*)d_in[6];
    const float* W2  = (const float*)d_in[7];
    const float* W3  = (const float*)d_in[8];
    const float* W4  = (const float*)d_in[9];
    float* out  = (float*)d_out;
    float* loss = out + (size_t)Bsz * 18;

    zero_loss_kernel<<<1, 64, 0, stream>>>(loss);
    tan_kernel<<<Bsz, NT, 0, stream>>>(x, y, emb, aw, ab,
                                       W0, W1, W2, W3, W4, out, loss);
}

// Round 9
// 159.479 us; speedup vs baseline: 1.0145x; 1.0145x over previous
//
#include <hip/hip_runtime.h>
#include <math.h>

#define Bsz 4096
#define Ssz 200
#define Dsz 64
#define NK  5
#define NT  512
#define ROWH 72    // halves per emb row (144 B), rows 0..223 (200..223 zero K-pad)
#define SA  224    // att_hf (fp16 scores) row stride, = K-pad

typedef _Float16 half_t;
typedef _Float16 h2 __attribute__((ext_vector_type(2)));
typedef _Float16 h8 __attribute__((ext_vector_type(8)));
typedef float    f4v __attribute__((ext_vector_type(4)));

__device__ inline h2 pk(float a, float b) {
    return __builtin_bit_cast(h2, __builtin_amdgcn_cvt_pkrtz(a, b));
}

__device__ inline float fast_tanh(float x) {
    float e = __expf(-2.0f * fabsf(x));
    float r = (1.0f - e) / (1.0f + e);
    return copysignf(r, x);
}

__global__ void zero_loss_kernel(float* loss) {
    if (threadIdx.x == 0) *loss = 0.0f;
}

__global__ __launch_bounds__(NT, 8) void tan_kernel(
    const int* __restrict__ x, const float* __restrict__ y,
    const float* __restrict__ emb_table,
    const float* __restrict__ att_w, const float* __restrict__ att_b,
    const float* __restrict__ W0, const float* __restrict__ W1,
    const float* __restrict__ W2, const float* __restrict__ W3,
    const float* __restrict__ W4,
    float* __restrict__ out_logit, float* __restrict__ loss_out)
{
    __shared__ alignas(16) half_t embh[224 * ROWH];    // 32256 B
    __shared__ alignas(16) float  att[NK][Ssz];        //  4000 B (logits)
    __shared__ alignas(16) half_t att_hf[NK * SA];     //  2240 B (scores fp16, K-pad)
    __shared__ alignas(16) half_t urph[2][NK][Dsz];    //  1280 B
    __shared__ float wu[18];                           //    72 B
    // total 39848 B -> 4 blocks/CU -> 32 waves/CU

    const int b   = blockIdx.x;
    const int tid = threadIdx.x;
    const int w   = tid >> 6;
    const int l   = tid & 63;
    const int lm  = l & 15;
    const int lq  = l >> 4;

    // ---- P0 (no own barrier): zero emb K-pad rows 200..223 ----
    {
        uint4 zz = {0, 0, 0, 0};
        uint4* zp = (uint4*)(embh + 200 * ROWH);   // 1728 halves = 216 uint4
        for (int i = tid; i < 216; i += NT) zp[i] = zz;
    }

    // ---- P1: coalesced gather, 16 lanes/row, 7 chunk-loads in flight ----
    {
        const int* xb = x + b * Ssz;
        float4 v[7];
#pragma unroll
        for (int p = 0; p < 7; ++p) {
            int i = tid + NT * p;
            if (i > Ssz * 16 - 1) i = Ssz * 16 - 1;
            const int s = i >> 4, c = i & 15;
            const int xi = xb[s];                  // 16-lane broadcast, L1-hot
            v[p] = ((const float4*)(emb_table + (size_t)xi * Dsz))[c];
        }
#pragma unroll
        for (int p = 0; p < 7; ++p) {
            const int i = tid + NT * p;
            if (p < 6 || i < Ssz * 16) {
                const int s = i >> 4, c = i & 15;
                h2 lo = pk(v[p].x, v[p].y);
                h2 hi = pk(v[p].z, v[p].w);
                uint2 u = { __builtin_bit_cast(unsigned, lo),
                            __builtin_bit_cast(unsigned, hi) };
                *(uint2*)(embh + s * ROWH + c * 4) = u;
            }
        }
    }
    __syncthreads();

    // ---- P1.5: attention logits via MFMA (A=aw regs, B=emb row-major b128) ----
    {
        h8 afrag[2];
#pragma unroll
        for (int st = 0; st < 2; ++st) {
            if (lm < NK) {
                const float4* ap = (const float4*)(att_w + lm * Dsz + 32 * st + 8 * lq);
                float4 a0 = ap[0], a1 = ap[1];
                union { h2 hh[4]; h8 v; } ua;
                ua.hh[0] = pk(a0.x, a0.y); ua.hh[1] = pk(a0.z, a0.w);
                ua.hh[2] = pk(a1.x, a1.y); ua.hh[3] = pk(a1.z, a1.w);
                afrag[st] = ua.v;
            } else {
                afrag[st] = (h8)(half_t)0;
            }
        }
        for (int t = w; t < 13; t += 8) {
            const int s = 16 * t + lm;            // <= 207; rows 200+ zeroed
            h8 b0 = *(const h8*)(embh + s * ROWH + 8 * lq);
            h8 b1 = *(const h8*)(embh + s * ROWH + 32 + 8 * lq);
            f4v acc = {0.f, 0.f, 0.f, 0.f};
            acc = __builtin_amdgcn_mfma_f32_16x16x32_f16(afrag[0], b0, acc, 0, 0, 0);
            acc = __builtin_amdgcn_mfma_f32_16x16x32_f16(afrag[1], b1, acc, 0, 0, 0);
            // C: row = lq*4+r = k, col = lm = s-in-tile
            const int sc = 16 * t + lm;
#pragma unroll
            for (int r = 0; r < 4; ++r) {
                const int k = lq * 4 + r;
                if (k < NK && sc < Ssz)
                    att[k][sc] = fast_tanh(acc[r] + att_b[k]);
            }
        }
    }
    __syncthreads();

    // ---- P2: softmax over s per k (waves 0..4); scores -> fp16 + zero K-pad ----
    if (w < NK) {
        const int k = w;
        float vals[4];
        float mx = -1e30f;
#pragma unroll
        for (int j = 0; j < 4; ++j) {
            int s = l + 64 * j;
            vals[j] = (s < Ssz) ? att[k][s] : -1e30f;
            mx = fmaxf(mx, vals[j]);
        }
#pragma unroll
        for (int m = 32; m >= 1; m >>= 1) mx = fmaxf(mx, __shfl_xor(mx, m));
        float sum = 0.f;
#pragma unroll
        for (int j = 0; j < 4; ++j) {
            vals[j] = __expf(vals[j] - mx);
            sum += vals[j];
        }
#pragma unroll
        for (int m = 32; m >= 1; m >>= 1) sum += __shfl_xor(sum, m);
        float inv = 1.0f / sum;
#pragma unroll
        for (int j = 0; j < 4; ++j) {
            int s = l + 64 * j;
            if (s < Ssz)            att_hf[k * SA + s] = (half_t)(vals[j] * inv);
            else if (s < SA)        att_hf[k * SA + s] = (half_t)0;   // K-pad
        }
    }
    __syncthreads();

    // ---- P3: user_rep via MFMA; wave w: d-tile (w&3), K-half (w>>2) ----
    {
        const int d0 = (w & 3) * 16;
        const int hh = w >> 2;
        const int nst   = hh ? 3 : 4;
        const int sbase = hh ? 128 : 0;
        f4v acc = {0.f, 0.f, 0.f, 0.f};
        for (int st = 0; st < nst; ++st) {
            const int s0 = sbase + 32 * st;
            h8 afr;
            if (lm < NK) afr = *(const h8*)(att_hf + lm * SA + s0 + lq * 8);
            else         afr = (h8)(half_t)0;
            union { h8 v; half_t e[8]; } ub;    // B[k=lq*8+j][n=lm] = emb[s0+lq*8+j][d0+lm]
#pragma unroll
            for (int j = 0; j < 8; ++j)
                ub.e[j] = embh[(s0 + lq * 8 + j) * ROWH + d0 + lm];
            acc = __builtin_amdgcn_mfma_f32_16x16x32_f16(afr, ub.v, acc, 0, 0, 0);
        }
        // C: row = lq*4+r = k, col = lm = d-in-tile
        if (lq == 0) {
#pragma unroll
            for (int r = 0; r < 4; ++r)
                urph[hh][r][d0 + lm] = (half_t)acc[r];
        } else if (lq == 1) {
            urph[hh][4][d0 + lm] = (half_t)acc[0];
        }
    }
    __syncthreads();

    // ---- P5: W_user[j] = ur[g(j)] . W_g[r(j)] (2-partial sum folded in) ----
    for (int j = w; j < 18; j += 8) {
        const float* Wp; int g, c0;
        if      (j < 2)  { g = 0; c0 = 0;  Wp = W0; }
        else if (j < 6)  { g = 1; c0 = 2;  Wp = W1; }
        else if (j < 10) { g = 2; c0 = 6;  Wp = W2; }
        else if (j < 12) { g = 3; c0 = 10; Wp = W3; }
        else             { g = 4; c0 = 12; Wp = W4; }
        float urv = (float)urph[0][g][l] + (float)urph[1][g][l];
        float p = urv * Wp[(j - c0) * Dsz + l];
#pragma unroll
        for (int m = 32; m >= 1; m >>= 1) p += __shfl_xor(p, m);
        if (l == 0) wu[j] = p;
    }
    __syncthreads();

    // ---- P6: per-group softmax -> logits; CE -> atomic loss ----
    if (w == 0) {
        float lossb = 0.f;
        if (l < NK) {
            const int LEN[5] = {2, 4, 4, 2, 6};
            const int C0[5]  = {0, 2, 6, 10, 12};
            const int g = l, c0 = C0[g], len = LEN[g];
            float* op = out_logit + (size_t)b * 18;
            const float* yp = y + (size_t)b * 18;
            float mx = -1e30f;
            for (int j = 0; j < len; ++j) mx = fmaxf(mx, wu[c0 + j]);
            float sum = 0.f;
            for (int j = 0; j < len; ++j) sum += __expf(wu[c0 + j] - mx);
            float inv = 1.0f / sum;
            float lse = mx + __logf(sum);
            for (int j = 0; j < len; ++j) {
                op[c0 + j] = __expf(wu[c0 + j] - mx) * inv;
                lossb += (lse - wu[c0 + j]) * yp[c0 + j];
            }
        }
#pragma unroll
        for (int m = 1; m <= 4; m <<= 1) lossb += __shfl_xor(lossb, m);
        if (l == 0) atomicAdd(loss_out, lossb * (1.0f / Bsz));
    }
}

extern "C" void kernel_launch(void* const* d_in, const int* in_sizes, int n_in,
                              void* d_out, int out_size, void* d_ws, size_t ws_size,
                              hipStream_t stream) {
    const int*   x   = (const int*)d_in[0];
    const float* y   = (const float*)d_in[1];
    const float* emb = (const float*)d_in[2];
    const float* aw  = (const float*)d_in[3];
    const float* ab  = (const float*)d_in[4];
    const float* W0  = (const float*)d_in[5];
    const float* W1  = (const float*)d_in[6];
    const float* W2  = (const float*)d_in[7];
    const float* W3  = (const float*)d_in[8];
    const float* W4  = (const float*)d_in[9];
    float* out  = (float*)d_out;
    float* loss = out + (size_t)Bsz * 18;

    zero_loss_kernel<<<1, 64, 0, stream>>>(loss);
    tan_kernel<<<Bsz, NT, 0, stream>>>(x, y, emb, aw, ab,
                                       W0, W1, W2, W3, W4, out, loss);
}

// Round 10
// 154.762 us; speedup vs baseline: 1.0454x; 1.0305x over previous
//
#include <hip/hip_runtime.h>
#include <math.h>

#define Bsz 4096
#define Ssz 200
#define Dsz 64
#define NK  5
#define NT  512
#define ROWH 72   // halves per emb row in LDS (144 B): b128-aligned, bank-balanced

typedef _Float16 half_t;
typedef _Float16 h2 __attribute__((ext_vector_type(2)));

__device__ inline h2 shfl_xor_h2(h2 v, int m) {
    int iv = __builtin_bit_cast(int, v);
    iv = __shfl_xor(iv, m);
    return __builtin_bit_cast(h2, iv);
}

__device__ inline h2 pk(float a, float b) {
    return __builtin_bit_cast(h2, __builtin_amdgcn_cvt_pkrtz(a, b));
}

__device__ inline float fdot2(h2 a, h2 b, float c) {
#if __has_builtin(__builtin_amdgcn_fdot2)
    return __builtin_amdgcn_fdot2(a, b, c, false);
#else
    return c + (float)a.x * (float)b.x + (float)a.y * (float)b.y;
#endif
}

__device__ inline float fast_tanh(float x) {
    float e = __expf(-2.0f * fabsf(x));
    float r = (1.0f - e) / (1.0f + e);
    return copysignf(r, x);
}

__global__ void zero_loss_kernel(float* loss) {
    if (threadIdx.x == 0) *loss = 0.0f;
}

__global__ __launch_bounds__(NT, 8) void tan_kernel(
    const int* __restrict__ x, const float* __restrict__ y,
    const float* __restrict__ emb_table,
    const float* __restrict__ att_w, const float* __restrict__ att_b,
    const float* __restrict__ W0, const float* __restrict__ W1,
    const float* __restrict__ W2, const float* __restrict__ W3,
    const float* __restrict__ W4,
    float* __restrict__ out_logit, float* __restrict__ loss_out)
{
    __shared__ alignas(16) half_t embh[Ssz * ROWH];      // 28800 B
    __shared__ alignas(16) float  att[NK][Ssz];          //  4000 B (logits, then scores)
    __shared__ alignas(16) h2     awh[NK * 32];          //  1280 B (att_w as h2)
    __shared__ alignas(16) half_t urph[8][NK][Dsz];      //  5120 B
    __shared__ alignas(16) int    xs[Ssz];               //   800 B
    __shared__ float wu[18];                             //    72 B
    // total ~40.1 KB -> 4 blocks/CU -> 32 waves/CU

    const int b   = blockIdx.x;
    const int tid = threadIdx.x;
    const int w   = tid >> 6;
    const int l   = tid & 63;

    // ---- P0: stage x indices (threads 0..199) + att_w->h2 (threads 256..415) ----
    if (tid < Ssz) xs[tid] = x[b * Ssz + tid];
    if (tid >= 256 && tid < 256 + NK * 32) {
        const int t = tid - 256;
        awh[t] = (h2){(half_t)att_w[2 * t], (half_t)att_w[2 * t + 1]};
    }
    __syncthreads();

    // ---- P1: coalesced gather, 16 lanes/row, 7 chunk-loads in flight/thread ----
    {
        float4 v[7];
#pragma unroll
        for (int p = 0; p < 7; ++p) {
            int i = tid + NT * p;
            if (i > Ssz * 16 - 1) i = Ssz * 16 - 1;
            const int s = i >> 4, c = i & 15;
            v[p] = ((const float4*)(emb_table + (size_t)xs[s] * Dsz))[c];
        }
#pragma unroll
        for (int p = 0; p < 7; ++p) {
            const int i = tid + NT * p;
            if (p < 6 || i < Ssz * 16) {
                const int s = i >> 4, c = i & 15;
                h2 lo = pk(v[p].x, v[p].y);
                h2 hi = pk(v[p].z, v[p].w);
                uint2 u = { __builtin_bit_cast(unsigned, lo),
                            __builtin_bit_cast(unsigned, hi) };
                *(uint2*)(embh + s * ROWH + c * 4) = u;
            }
        }
    }
    __syncthreads();

    // ---- P1.5: attention logits via fdot2, 2 threads/row ----
    if (tid < 2 * Ssz) {
        const int s = tid >> 1, h = tid & 1;
        union { uint4 q[4]; h2 hh[16]; } ue;
        const uint4* rp = (const uint4*)(embh + s * ROWH + h * 32);
#pragma unroll
        for (int i = 0; i < 4; ++i) ue.q[i] = rp[i];
        float acc[NK];
#pragma unroll 1
        for (int k = 0; k < NK; ++k) {
            union { uint4 q[4]; h2 hh[16]; } ua;
            const uint4* ap = (const uint4*)(awh + k * 32 + h * 16);
#pragma unroll
            for (int i = 0; i < 4; ++i) ua.q[i] = ap[i];
            float a = 0.f;
#pragma unroll
            for (int i = 0; i < 16; ++i) a = fdot2(ue.hh[i], ua.hh[i], a);
            acc[k] = a;
        }
#pragma unroll
        for (int k = 0; k < NK; ++k) acc[k] += __shfl_xor(acc[k], 1);
        if (h == 0) {
#pragma unroll
            for (int k = 0; k < NK; ++k) att[k][s] = fast_tanh(acc[k] + att_b[k]);
        }
    }
    __syncthreads();

    // ---- P2: softmax over s for each k (waves 0..4) ----
    if (w < NK) {
        const int k = w;
        float vals[4];
        float mx = -1e30f;
#pragma unroll
        for (int j = 0; j < 4; ++j) {
            int s = l + 64 * j;
            vals[j] = (s < Ssz) ? att[k][s] : -1e30f;
            mx = fmaxf(mx, vals[j]);
        }
#pragma unroll
        for (int m = 32; m >= 1; m >>= 1) mx = fmaxf(mx, __shfl_xor(mx, m));
        float sum = 0.f;
#pragma unroll
        for (int j = 0; j < 4; ++j) {
            vals[j] = __expf(vals[j] - mx);
            sum += vals[j];
        }
#pragma unroll
        for (int m = 32; m >= 1; m >>= 1) sum += __shfl_xor(sum, m);
        float inv = 1.0f / sum;
#pragma unroll
        for (int j = 0; j < 4; ++j) {
            int s = l + 64 * j;
            if (s < Ssz) att[k][s] = vals[j] * inv;
        }
    }
    __syncthreads();

    // ---- P3: user_rep, packed-fp16; thread (c=tid&7, j=tid>>3), s = j + 64t ----
    {
        const int c = tid & 7;           // d-frag [c*8, c*8+8)
        const int j = tid >> 3;          // 64 s-groups
        h2 acc[NK][4];
#pragma unroll
        for (int k = 0; k < NK; ++k)
#pragma unroll
            for (int i = 0; i < 4; ++i) acc[k][i] = (h2){(half_t)0, (half_t)0};
#pragma unroll
        for (int t = 0; t < 4; ++t) {
            const int s = j + 64 * t;
            if (s < Ssz) {
                union { uint4 q; h2 hh[4]; } u;
                u.q = *(const uint4*)(embh + s * ROWH + c * 8);
#pragma unroll
                for (int k = 0; k < NK; ++k) {
                    half_t f = (half_t)att[k][s];
                    h2 sc = (h2){f, f};
#pragma unroll
                    for (int i = 0; i < 4; ++i) acc[k][i] += u.hh[i] * sc;
                }
            }
        }
        // reduce across the 8 j's within this wave (lane bits 3,4,5)
#pragma unroll
        for (int k = 0; k < NK; ++k)
#pragma unroll
            for (int i = 0; i < 4; ++i) {
                acc[k][i] += shfl_xor_h2(acc[k][i], 8);
                acc[k][i] += shfl_xor_h2(acc[k][i], 16);
                acc[k][i] += shfl_xor_h2(acc[k][i], 32);
            }
        if (l < 8) {
#pragma unroll
            for (int k = 0; k < NK; ++k) {
                union { h2 a[4]; uint4 q; } uu;
#pragma unroll
                for (int i = 0; i < 4; ++i) uu.a[i] = acc[k][i];
                *(uint4*)(&urph[w][k][l * 8]) = uu.q;
            }
        }
    }
    __syncthreads();

    // ---- P5: W_user[j] = ur[g(j)] . W_g[r(j)] (8-partial sum folded in) ----
    for (int j = w; j < 18; j += 8) {
        const float* Wp; int g, c0;
        if      (j < 2)  { g = 0; c0 = 0;  Wp = W0; }
        else if (j < 6)  { g = 1; c0 = 2;  Wp = W1; }
        else if (j < 10) { g = 2; c0 = 6;  Wp = W2; }
        else if (j < 12) { g = 3; c0 = 10; Wp = W3; }
        else             { g = 4; c0 = 12; Wp = W4; }
        float urv = 0.f;
#pragma unroll
        for (int jj = 0; jj < 8; ++jj) urv += (float)urph[jj][g][l];
        float p = urv * Wp[(j - c0) * Dsz + l];
#pragma unroll
        for (int m = 32; m >= 1; m >>= 1) p += __shfl_xor(p, m);
        if (l == 0) wu[j] = p;
    }
    __syncthreads();

    // ---- P6: per-group softmax -> logits; CE -> atomic loss ----
    if (w == 0) {
        float lossb = 0.f;
        if (l < NK) {
            const int LEN[5] = {2, 4, 4, 2, 6};
            const int C0[5]  = {0, 2, 6, 10, 12};
            const int g = l, c0 = C0[g], len = LEN[g];
            float* op = out_logit + (size_t)b * 18;
            const float* yp = y + (size_t)b * 18;
            float mx = -1e30f;
            for (int j = 0; j < len; ++j) mx = fmaxf(mx, wu[c0 + j]);
            float sum = 0.f;
            for (int j = 0; j < len; ++j) sum += __expf(wu[c0 + j] - mx);
            float inv = 1.0f / sum;
            float lse = mx + __logf(sum);
            for (int j = 0; j < len; ++j) {
                op[c0 + j] = __expf(wu[c0 + j] - mx) * inv;
                lossb += (lse - wu[c0 + j]) * yp[c0 + j];
            }
        }
#pragma unroll
        for (int m = 1; m <= 4; m <<= 1) lossb += __shfl_xor(lossb, m);
        if (l == 0) atomicAdd(loss_out, lossb * (1.0f / Bsz));
    }
}

extern "C" void kernel_launch(void* const* d_in, const int* in_sizes, int n_in,
                              void* d_out, int out_size, void* d_ws, size_t ws_size,
                              hipStream_t stream) {
    const int*   x   = (const int*)d_in[0];
    const float* y   = (const float*)d_in[1];
    const float* emb = (const float*)d_in[2];
    const float* aw  = (const float*)d_in[3];
    const float* ab  = (const float*)d_in[4];
    const float* W0  = (const float*)d_in[5];
    const float* W1  = (const float*)d_in[6];
    const float* W2  = (const float*)d_in[7];
    const float* W3  = (const float*)d_in[8];
    const float* W4  = (const float*)d_in[9];
    float* out  = (float*)d_out;
    float* loss = out + (size_t)Bsz * 18;

    zero_loss_kernel<<<1, 64, 0, stream>>>(loss);
    tan_kernel<<<Bsz, NT, 0, stream>>>(x, y, emb, aw, ab,
                                       W0, W1, W2, W3, W4, out, loss);
}